// Round 7
// baseline (328.433 us; speedup 1.0000x reference)
//
#include <hip/hip_runtime.h>
#include <hip/hip_bf16.h>

typedef __attribute__((ext_vector_type(8))) short short8;
typedef __attribute__((ext_vector_type(4))) float f32x4;

#define N_NODES 20000
#define N_EDGES 320000
#define NFEAT 512
#define NHID 1024

__device__ __forceinline__ float bf2f(unsigned short u) {
    union { unsigned int i; float f; } c; c.i = ((unsigned int)u) << 16; return c.f;
}
__device__ __forceinline__ unsigned short f2bf(float f) {
    union { float f; unsigned int i; } c; c.f = f;
    unsigned int x = c.i;
    return (unsigned short)((x + 0x7fffu + ((x >> 16) & 1u)) >> 16);
}

__device__ __forceinline__ void gload_lds16(const void* g, void* l) {
    __builtin_amdgcn_global_load_lds(
        (const __attribute__((address_space(1))) void*)g,
        (__attribute__((address_space(3))) void*)l, 16, 0, 0);
}

// ---------------- CSR build ----------------

__global__ void hist_kernel(const int* __restrict__ dst, int* __restrict__ deg, int E) {
    int e = blockIdx.x * 256 + threadIdx.x;
    if (e < E) atomicAdd(&deg[dst[e]], 1);
}

__global__ __launch_bounds__(1024) void scan_kernel(const int* __restrict__ deg,
                                                    int* __restrict__ row_ptr,
                                                    int* __restrict__ cursor, int n) {
    __shared__ int sdata[1024];
    const int t = threadIdx.x;
    constexpr int CH = 20;  // 1024*20 = 20480 >= 20000
    int base = t * CH;
    int local[CH];
    int sum = 0;
#pragma unroll
    for (int i = 0; i < CH; ++i) {
        int idx = base + i;
        int v = (idx < n) ? deg[idx] : 0;
        local[i] = sum;
        sum += v;
    }
    sdata[t] = sum;
    __syncthreads();
    for (int off = 1; off < 1024; off <<= 1) {
        int v = (t >= off) ? sdata[t - off] : 0;
        __syncthreads();
        sdata[t] += v;
        __syncthreads();
    }
    int prev = (t == 0) ? 0 : sdata[t - 1];
#pragma unroll
    for (int i = 0; i < CH; ++i) {
        int idx = base + i;
        if (idx < n) {
            int p = prev + local[i];
            row_ptr[idx] = p;
            cursor[idx]  = p;
        }
    }
    if (t == 1023) row_ptr[n] = sdata[1023];
}

__global__ void fill_kernel(const int* __restrict__ src, const int* __restrict__ dst,
                            const float* __restrict__ vals, int* __restrict__ cursor,
                            int* __restrict__ csr_src, float* __restrict__ csr_val, int E) {
    int e = blockIdx.x * 256 + threadIdx.x;
    if (e < E) {
        int d = dst[e];
        int pos = atomicAdd(&cursor[d], 1);
        csr_src[pos] = src[e];
        csr_val[pos] = vals[e];
    }
}

// ------------- W transpose + bf16 convert:  Wt[n][k] = W[k][n] -------------

__global__ void transpose_cvt(const float* __restrict__ W, unsigned short* __restrict__ Wt,
                              int K, int N) {
    __shared__ float tile[32][33];
    int ntx = N >> 5;
    int k0 = (blockIdx.x / ntx) << 5;
    int n0 = (blockIdx.x % ntx) << 5;
    int tx = threadIdx.x & 31, ty = threadIdx.x >> 5;  // ty 0..7
#pragma unroll
    for (int i = 0; i < 32; i += 8)
        tile[ty + i][tx] = W[(size_t)(k0 + ty + i) * N + n0 + tx];
    __syncthreads();
#pragma unroll
    for (int i = 0; i < 32; i += 8)
        Wt[(size_t)(n0 + ty + i) * K + k0 + tx] = f2bf(tile[tx][ty + i]);
}

// ------------- f32 -> bf16 convert (x) -------------

__global__ void cvt_bf16_kernel(const float* __restrict__ x, unsigned short* __restrict__ xb,
                                int n8) {
    int i = blockIdx.x * 256 + threadIdx.x;
    if (i < n8) {
        f32x4 v0 = ((const f32x4*)x)[i * 2];
        f32x4 v1 = ((const f32x4*)x)[i * 2 + 1];
        short8 o;
#pragma unroll
        for (int j = 0; j < 4; ++j) {
            o[j]     = (short)f2bf(v0[j]);
            o[4 + j] = (short)f2bf(v1[j]);
        }
        ((short8*)xb)[i] = o;
    }
}

// ------------- dropout mask bit-pack: bit=1 iff u > 0.5 -------------

__global__ __launch_bounds__(256) void mask_kernel(const float* __restrict__ u,
                                                   unsigned int* __restrict__ mask) {
    __shared__ unsigned char nib[256];
    size_t base = (size_t)blockIdx.x * 1024;
    int t = threadIdx.x;
    f32x4 v = ((const f32x4*)(u + base))[t];
    unsigned n = (v[0] > 0.5f ? 1u : 0u) | (v[1] > 0.5f ? 2u : 0u) |
                 (v[2] > 0.5f ? 4u : 0u) | (v[3] > 0.5f ? 8u : 0u);
    nib[t] = (unsigned char)n;
    __syncthreads();
    if (t < 32) {
        unsigned w = 0;
#pragma unroll
        for (int i = 0; i < 8; ++i) w |= (unsigned)nib[t * 8 + i] << (i * 4);
        mask[base / 32 + t] = w;
    }
}

// ------------- aggregation 1:  agg[d] = sum_e val_e * xbf[src_e]  (bf16 in, bf16 out) -------------

__global__ __launch_bounds__(64) void agg1_kernel(const unsigned short* __restrict__ xbf,
                                                  const int* __restrict__ csr_src,
                                                  const float* __restrict__ csr_val,
                                                  const int* __restrict__ row_ptr,
                                                  unsigned short* __restrict__ agg) {
    int d = blockIdx.x;
    int l = threadIdx.x;  // 0..63, 8 bf16 each -> 512
    int e0 = row_ptr[d], e1 = row_ptr[d + 1];
    f32x4 a0 = {0.f, 0.f, 0.f, 0.f}, a1 = {0.f, 0.f, 0.f, 0.f};
    int e = e0;
    for (; e + 3 < e1; e += 4) {
        int s0 = csr_src[e], s1 = csr_src[e + 1], s2 = csr_src[e + 2], s3 = csr_src[e + 3];
        float v0 = csr_val[e], v1 = csr_val[e + 1], v2 = csr_val[e + 2], v3 = csr_val[e + 3];
        short8 w0 = *(const short8*)&xbf[(size_t)s0 * NFEAT + l * 8];
        short8 w1 = *(const short8*)&xbf[(size_t)s1 * NFEAT + l * 8];
        short8 w2 = *(const short8*)&xbf[(size_t)s2 * NFEAT + l * 8];
        short8 w3 = *(const short8*)&xbf[(size_t)s3 * NFEAT + l * 8];
#pragma unroll
        for (int j = 0; j < 4; ++j) {
            a0[j] += v0 * bf2f((unsigned short)w0[j]);
            a1[j] += v0 * bf2f((unsigned short)w0[4 + j]);
            a0[j] += v1 * bf2f((unsigned short)w1[j]);
            a1[j] += v1 * bf2f((unsigned short)w1[4 + j]);
            a0[j] += v2 * bf2f((unsigned short)w2[j]);
            a1[j] += v2 * bf2f((unsigned short)w2[4 + j]);
            a0[j] += v3 * bf2f((unsigned short)w3[j]);
            a1[j] += v3 * bf2f((unsigned short)w3[4 + j]);
        }
    }
    for (; e < e1; ++e) {
        int s0 = csr_src[e];
        float v0 = csr_val[e];
        short8 w0 = *(const short8*)&xbf[(size_t)s0 * NFEAT + l * 8];
#pragma unroll
        for (int j = 0; j < 4; ++j) {
            a0[j] += v0 * bf2f((unsigned short)w0[j]);
            a1[j] += v0 * bf2f((unsigned short)w0[4 + j]);
        }
    }
    short8 o;
#pragma unroll
    for (int j = 0; j < 4; ++j) {
        o[j]     = (short)f2bf(a0[j]);
        o[4 + j] = (short)f2bf(a1[j]);
    }
    *(short8*)&agg[(size_t)d * NFEAT + l * 8] = o;
}

// ------------- aggregation 2:  out[d] = b2 + sum_e val_e * s2[src_e]  (bf16 in, f32 out) -------------

__global__ __launch_bounds__(64) void agg2_kernel(const unsigned short* __restrict__ s2,
                                                  const int* __restrict__ csr_src,
                                                  const float* __restrict__ csr_val,
                                                  const int* __restrict__ row_ptr,
                                                  const float* __restrict__ b2,
                                                  float* __restrict__ out) {
    int d = blockIdx.x;
    int l = threadIdx.x;  // 0..63, 8 elems each -> 512
    int e0 = row_ptr[d], e1 = row_ptr[d + 1];
    f32x4 a0 = ((const f32x4*)b2)[l * 2];
    f32x4 a1 = ((const f32x4*)b2)[l * 2 + 1];
    int e = e0;
    for (; e + 3 < e1; e += 4) {
        int s0 = csr_src[e], s1 = csr_src[e + 1], s2i = csr_src[e + 2], s3 = csr_src[e + 3];
        float v0 = csr_val[e], v1 = csr_val[e + 1], v2 = csr_val[e + 2], v3 = csr_val[e + 3];
        short8 w0 = *(const short8*)&s2[(size_t)s0 * NFEAT + l * 8];
        short8 w1 = *(const short8*)&s2[(size_t)s1 * NFEAT + l * 8];
        short8 w2 = *(const short8*)&s2[(size_t)s2i * NFEAT + l * 8];
        short8 w3 = *(const short8*)&s2[(size_t)s3 * NFEAT + l * 8];
#pragma unroll
        for (int j = 0; j < 4; ++j) {
            a0[j] += v0 * bf2f((unsigned short)w0[j]);
            a1[j] += v0 * bf2f((unsigned short)w0[4 + j]);
            a0[j] += v1 * bf2f((unsigned short)w1[j]);
            a1[j] += v1 * bf2f((unsigned short)w1[4 + j]);
            a0[j] += v2 * bf2f((unsigned short)w2[j]);
            a1[j] += v2 * bf2f((unsigned short)w2[4 + j]);
            a0[j] += v3 * bf2f((unsigned short)w3[j]);
            a1[j] += v3 * bf2f((unsigned short)w3[4 + j]);
        }
    }
    for (; e < e1; ++e) {
        int s0 = csr_src[e];
        float v0 = csr_val[e];
        short8 w0 = *(const short8*)&s2[(size_t)s0 * NFEAT + l * 8];
#pragma unroll
        for (int j = 0; j < 4; ++j) {
            a0[j] += v0 * bf2f((unsigned short)w0[j]);
            a1[j] += v0 * bf2f((unsigned short)w0[4 + j]);
        }
    }
    *(f32x4*)&out[(size_t)d * NFEAT + l * 8]     = a0;
    *(f32x4*)&out[(size_t)d * NFEAT + l * 8 + 4] = a1;
}

// ------------- barrier-free MFMA GEMM:  C[M,N] = A[M,K] * Bt[N,K]^T -------------
// Block tile: 64 (M) x 256 (N), 4 waves; each wave owns an independent 64x64
// output strip. A (64 rows x 512-col K-half) staged ONCE into XOR-swizzled LDS
// (64 KB) -> only 2 barriers per K-half, none in the inner loop. B fragments
// read directly from global (weights are <=2 MB, L2-resident on every XCD).
// Inner loop is fence-free: compiler software-pipelines, 8 waves/CU hide L2 lat.
// EPI==1: C = bf16(relu(acc+bias) * 2 * maskbit)

template <int EPI, int KTOT>
__global__ __launch_bounds__(256, 2) void gemm_nolds(
    const unsigned short* __restrict__ A,
    const unsigned short* __restrict__ Bt,
    unsigned short* __restrict__ C,
    int M, int N,
    const float* __restrict__ bias,
    const unsigned int* __restrict__ mask) {
    __shared__ __align__(16) unsigned short lA[64 * 512];  // 64 KB

    // bijective XCD swizzle (m204)
    const int nwg = gridDim.x;
    const int bid = blockIdx.x;
    const int q = nwg >> 3, r = nwg & 7;
    const int xcd = bid & 7, pos = bid >> 3;
    const int swz = (xcd < r ? xcd * (q + 1) : r * (q + 1) + (xcd - r) * q) + pos;

    const int nt = N >> 8;            // 256-col strips
    const int bm = swz / nt;
    const int bn = swz % nt;
    const int row0 = bm << 6;
    const int col0 = (bn << 8) + ((threadIdx.x >> 6) << 6);  // wave's 64-col strip
    const int lane = threadIdx.x & 63;
    const int wid = threadIdx.x >> 6;
    const int rl = lane & 15;
    const int kq = lane >> 4;         // 0..3

    f32x4 acc[4][4] = {};

    constexpr int KH = KTOT / 512;
#pragma unroll 1
    for (int kh = 0; kh < KH; ++kh) {
        if (kh) __syncthreads();      // all reads of lA done before restage
        {
            const int koff = kh * 512;
#pragma unroll
            for (int r8 = 0; r8 < 16; ++r8) {
                int rr = wid * 16 + r8;
                int ga = row0 + rr; if (ga >= M) ga = M - 1;
                // source slot pre-swizzled: LDS slot l holds global slot l^(rr&7)
                gload_lds16(A + (size_t)ga * KTOT + koff + ((lane ^ (rr & 7)) << 3),
                            &lA[rr * 512]);
            }
        }
        __syncthreads();              // compiler drains vmcnt before barrier

#pragma unroll 2
        for (int kt = 0; kt < 8; ++kt) {
#pragma unroll
            for (int ks = 0; ks < 2; ++ks) {
                const int s = kt * 8 + ks * 4 + kq;   // 16B slot 0..63
                short8 af[4], bfr[4];
#pragma unroll
                for (int m = 0; m < 4; ++m) {
                    int rr = m * 16 + rl;
                    af[m] = *(const short8*)&lA[rr * 512 + ((s ^ (rr & 7)) << 3)];
                }
#pragma unroll
                for (int n = 0; n < 4; ++n) {
                    int br = col0 + n * 16 + rl;
                    bfr[n] = *(const short8*)&Bt[(size_t)br * KTOT + kh * 512 +
                                                 kt * 64 + ks * 32 + kq * 8];
                }
#pragma unroll
                for (int m = 0; m < 4; ++m)
#pragma unroll
                    for (int n = 0; n < 4; ++n)
                        acc[m][n] = __builtin_amdgcn_mfma_f32_16x16x32_bf16(
                            af[m], bfr[n], acc[m][n], 0, 0, 0);
            }
        }
    }

    // epilogue: C/D layout col = lane&15, row = (lane>>4)*4 + j
    const int crow = kq * 4;
#pragma unroll
    for (int m = 0; m < 4; ++m) {
#pragma unroll
        for (int n = 0; n < 4; ++n) {
            int gr0 = row0 + m * 16 + crow;
            int gc = col0 + n * 16 + rl;
#pragma unroll
            for (int j = 0; j < 4; ++j) {
                int gr = gr0 + j;
                if (gr < M) {
                    float v = acc[m][n][j];
                    if (EPI == 1) {
                        v += bias[gc];
                        v = v > 0.f ? v : 0.f;
                        unsigned w = mask[(size_t)gr * (N >> 5) + (gc >> 5)];
                        v = ((w >> (gc & 31)) & 1u) ? v * 2.0f : 0.0f;
                    }
                    C[(size_t)gr * N + gc] = f2bf(v);
                }
            }
        }
    }
}

// ---------------- launch ----------------

extern "C" void kernel_launch(void* const* d_in, const int* in_sizes, int n_in,
                              void* d_out, int out_size, void* d_ws, size_t ws_size,
                              hipStream_t stream) {
    const float* x        = (const float*)d_in[0];
    const float* W1       = (const float*)d_in[1];
    const float* b1       = (const float*)d_in[2];
    const float* W2       = (const float*)d_in[3];
    const float* b2       = (const float*)d_in[4];
    const float* adj_vals = (const float*)d_in[5];
    const float* u_drop   = (const float*)d_in[6];
    const int*   src      = (const int*)d_in[7];
    const int*   dst      = (const int*)d_in[8];
    float* out = (float*)d_out;

    char* p = (char*)d_ws;
    auto take = [&](size_t bytes) {
        char* q = p;
        p += (bytes + 255) & ~(size_t)255;
        return q;
    };
    int* deg        = (int*)take((size_t)N_NODES * 4);
    int* row_ptr    = (int*)take((size_t)(N_NODES + 1) * 4);
    int* cursor     = (int*)take((size_t)N_NODES * 4);
    int* csr_src    = (int*)take((size_t)N_EDGES * 4);
    float* csr_val  = (float*)take((size_t)N_EDGES * 4);
    unsigned short* w1t   = (unsigned short*)take((size_t)NFEAT * NHID * 2);
    unsigned short* w2t   = (unsigned short*)take((size_t)NFEAT * NHID * 2);
    unsigned short* xbf   = (unsigned short*)take((size_t)N_NODES * NFEAT * 2);
    unsigned short* agg1b = (unsigned short*)take((size_t)N_NODES * NFEAT * 2);
    unsigned short* hbuf  = (unsigned short*)take((size_t)N_NODES * NHID * 2);
    unsigned short* s2buf = (unsigned short*)take((size_t)N_NODES * NFEAT * 2);
    unsigned int* umask   = (unsigned int*)take((size_t)N_NODES * (NHID / 32) * 4);

    hipMemsetAsync(deg, 0, (size_t)N_NODES * 4, stream);
    hist_kernel<<<(N_EDGES + 255) / 256, 256, 0, stream>>>(dst, deg, N_EDGES);
    scan_kernel<<<1, 1024, 0, stream>>>(deg, row_ptr, cursor, N_NODES);
    fill_kernel<<<(N_EDGES + 255) / 256, 256, 0, stream>>>(src, dst, adj_vals, cursor,
                                                           csr_src, csr_val, N_EDGES);
    transpose_cvt<<<(NFEAT / 32) * (NHID / 32), 256, 0, stream>>>(W1, w1t, NFEAT, NHID);
    transpose_cvt<<<(NHID / 32) * (NFEAT / 32), 256, 0, stream>>>(W2, w2t, NHID, NFEAT);
    cvt_bf16_kernel<<<(N_NODES * NFEAT / 8 + 255) / 256, 256, 0, stream>>>(
        x, xbf, N_NODES * NFEAT / 8);
    mask_kernel<<<N_NODES * NHID / 1024, 256, 0, stream>>>(u_drop, umask);

    agg1_kernel<<<N_NODES, 64, 0, stream>>>(xbf, csr_src, csr_val, row_ptr, agg1b);

    const int mt = (N_NODES + 63) / 64;  // 313
    gemm_nolds<1, NFEAT><<<mt * (NHID / 256), 256, 0, stream>>>(agg1b, w1t, hbuf,
                                                                N_NODES, NHID, b1, umask);
    gemm_nolds<0, NHID><<<mt * (NFEAT / 256), 256, 0, stream>>>(hbuf, w2t, s2buf,
                                                                N_NODES, NFEAT, nullptr, nullptr);

    agg2_kernel<<<N_NODES, 64, 0, stream>>>(s2buf, csr_src, csr_val, row_ptr, b2, out);
}

// Round 8
// 297.607 us; speedup vs baseline: 1.1036x; 1.1036x over previous
//
#include <hip/hip_runtime.h>
#include <hip/hip_bf16.h>

typedef __attribute__((ext_vector_type(8))) short short8;
typedef __attribute__((ext_vector_type(4))) float f32x4;

#define N_NODES 20000
#define N_EDGES 320000
#define NFEAT 512
#define NHID 1024
#define MBTOT 1252   // ceil(20000/16)=1250, +2 pad for the 64-row tail

__device__ __forceinline__ float bf2f(unsigned short u) {
    union { unsigned int i; float f; } c; c.i = ((unsigned int)u) << 16; return c.f;
}
__device__ __forceinline__ unsigned short f2bf(float f) {
    union { float f; unsigned int i; } c; c.f = f;
    unsigned int x = c.i;
    return (unsigned short)((x + 0x7fffu + ((x >> 16) & 1u)) >> 16);
}

// ---------------- CSR build ----------------

__global__ void hist_kernel(const int* __restrict__ dst, int* __restrict__ deg, int E) {
    int e = blockIdx.x * 256 + threadIdx.x;
    if (e < E) atomicAdd(&deg[dst[e]], 1);
}

__global__ __launch_bounds__(1024) void scan_kernel(const int* __restrict__ deg,
                                                    int* __restrict__ row_ptr,
                                                    int* __restrict__ cursor, int n) {
    __shared__ int sdata[1024];
    const int t = threadIdx.x;
    constexpr int CH = 20;
    int base = t * CH;
    int local[CH];
    int sum = 0;
#pragma unroll
    for (int i = 0; i < CH; ++i) {
        int idx = base + i;
        int v = (idx < n) ? deg[idx] : 0;
        local[i] = sum;
        sum += v;
    }
    sdata[t] = sum;
    __syncthreads();
    for (int off = 1; off < 1024; off <<= 1) {
        int v = (t >= off) ? sdata[t - off] : 0;
        __syncthreads();
        sdata[t] += v;
        __syncthreads();
    }
    int prev = (t == 0) ? 0 : sdata[t - 1];
#pragma unroll
    for (int i = 0; i < CH; ++i) {
        int idx = base + i;
        if (idx < n) {
            int p = prev + local[i];
            row_ptr[idx] = p;
            cursor[idx]  = p;
        }
    }
    if (t == 1023) row_ptr[n] = sdata[1023];
}

__global__ void fill_kernel(const int* __restrict__ src, const int* __restrict__ dst,
                            const float* __restrict__ vals, int* __restrict__ cursor,
                            int* __restrict__ csr_src, float* __restrict__ csr_val, int E) {
    int e = blockIdx.x * 256 + threadIdx.x;
    if (e < E) {
        int d = dst[e];
        int pos = atomicAdd(&cursor[d], 1);
        csr_src[pos] = src[e];
        csr_val[pos] = vals[e];
    }
}

// ------------- W transpose + bf16 + MFMA-fragment pack -------------
// W[k][n] (f32, K x N) -> Bp[nb][kb][lane=kq*16+rl][j] = bf16 W[kb*32+kq*8+j][nb*16+rl]

__global__ void transpose_cvt_pk(const float* __restrict__ W, unsigned short* __restrict__ Bp,
                                 int K, int N) {
    __shared__ float tile[32][33];
    const int KT = K >> 5;
    int ntx = N >> 5;
    int k0 = (blockIdx.x / ntx) << 5;
    int n0 = (blockIdx.x % ntx) << 5;
    int tx = threadIdx.x & 31, ty = threadIdx.x >> 5;  // ty 0..7
#pragma unroll
    for (int i = 0; i < 32; i += 8)
        tile[ty + i][tx] = W[(size_t)(k0 + ty + i) * N + n0 + tx];
    __syncthreads();
#pragma unroll
    for (int i = 0; i < 32; i += 8) {
        int n = n0 + ty + i;
        int k = k0 + tx;
        int nb = n >> 4, rl = n & 15;
        int kb = k >> 5, kq = (k & 31) >> 3, j = k & 7;
        Bp[((((size_t)nb * KT + kb) * 64) + kq * 16 + rl) * 8 + j] = f2bf(tile[tx][ty + i]);
    }
}

// ------------- f32 -> bf16 convert (x) -------------

__global__ void cvt_bf16_kernel(const float* __restrict__ x, unsigned short* __restrict__ xb,
                                int n8) {
    int i = blockIdx.x * 256 + threadIdx.x;
    if (i < n8) {
        f32x4 v0 = ((const f32x4*)x)[i * 2];
        f32x4 v1 = ((const f32x4*)x)[i * 2 + 1];
        short8 o;
#pragma unroll
        for (int j = 0; j < 4; ++j) {
            o[j]     = (short)f2bf(v0[j]);
            o[4 + j] = (short)f2bf(v1[j]);
        }
        ((short8*)xb)[i] = o;
    }
}

// ------------- dropout mask bit-pack: bit=1 iff u > 0.5 -------------

__global__ __launch_bounds__(256) void mask_kernel(const float* __restrict__ u,
                                                   unsigned int* __restrict__ mask) {
    __shared__ unsigned char nib[256];
    size_t base = (size_t)blockIdx.x * 1024;
    int t = threadIdx.x;
    f32x4 v = ((const f32x4*)(u + base))[t];
    unsigned n = (v[0] > 0.5f ? 1u : 0u) | (v[1] > 0.5f ? 2u : 0u) |
                 (v[2] > 0.5f ? 4u : 0u) | (v[3] > 0.5f ? 8u : 0u);
    nib[t] = (unsigned char)n;
    __syncthreads();
    if (t < 32) {
        unsigned w = 0;
#pragma unroll
        for (int i = 0; i < 8; ++i) w |= (unsigned)nib[t * 8 + i] << (i * 4);
        mask[base / 32 + t] = w;
    }
}

// ------------- aggregation 1: packed-A output -------------
// A1p[mb][kb][lane][j] = bf16( sum_e val_e * x[src_e][kb*32+kq*8+j] ), mb=d/16, rl=d%16
// thread t handles feats t*8..t*8+7 -> kb=t/4, kq=t%4

__global__ __launch_bounds__(64) void agg1_kernel(const unsigned short* __restrict__ xbf,
                                                  const int* __restrict__ csr_src,
                                                  const float* __restrict__ csr_val,
                                                  const int* __restrict__ row_ptr,
                                                  unsigned short* __restrict__ A1p) {
    int d = blockIdx.x;
    int l = threadIdx.x;  // 0..63
    int e0 = row_ptr[d], e1 = row_ptr[d + 1];
    f32x4 a0 = {0.f, 0.f, 0.f, 0.f}, a1 = {0.f, 0.f, 0.f, 0.f};
    int e = e0;
    for (; e + 3 < e1; e += 4) {
        int s0 = csr_src[e], s1 = csr_src[e + 1], s2 = csr_src[e + 2], s3 = csr_src[e + 3];
        float v0 = csr_val[e], v1 = csr_val[e + 1], v2 = csr_val[e + 2], v3 = csr_val[e + 3];
        short8 w0 = *(const short8*)&xbf[(size_t)s0 * NFEAT + l * 8];
        short8 w1 = *(const short8*)&xbf[(size_t)s1 * NFEAT + l * 8];
        short8 w2 = *(const short8*)&xbf[(size_t)s2 * NFEAT + l * 8];
        short8 w3 = *(const short8*)&xbf[(size_t)s3 * NFEAT + l * 8];
#pragma unroll
        for (int j = 0; j < 4; ++j) {
            a0[j] += v0 * bf2f((unsigned short)w0[j]);
            a1[j] += v0 * bf2f((unsigned short)w0[4 + j]);
            a0[j] += v1 * bf2f((unsigned short)w1[j]);
            a1[j] += v1 * bf2f((unsigned short)w1[4 + j]);
            a0[j] += v2 * bf2f((unsigned short)w2[j]);
            a1[j] += v2 * bf2f((unsigned short)w2[4 + j]);
            a0[j] += v3 * bf2f((unsigned short)w3[j]);
            a1[j] += v3 * bf2f((unsigned short)w3[4 + j]);
        }
    }
    for (; e < e1; ++e) {
        int s0 = csr_src[e];
        float v0 = csr_val[e];
        short8 w0 = *(const short8*)&xbf[(size_t)s0 * NFEAT + l * 8];
#pragma unroll
        for (int j = 0; j < 4; ++j) {
            a0[j] += v0 * bf2f((unsigned short)w0[j]);
            a1[j] += v0 * bf2f((unsigned short)w0[4 + j]);
        }
    }
    short8 o;
#pragma unroll
    for (int j = 0; j < 4; ++j) {
        o[j]     = (short)f2bf(a0[j]);
        o[4 + j] = (short)f2bf(a1[j]);
    }
    // packed write: feats l*8.. -> kb = l/4, kq = l%4
    size_t idx = ((((size_t)(d >> 4) * (NFEAT / 32) + (l >> 2)) * 64) + (l & 3) * 16 + (d & 15)) * 8;
    *(short8*)&A1p[idx] = o;
}

// ------------- aggregation 2 (bf16 in row-major, f32 out) -------------

__global__ __launch_bounds__(64) void agg2_kernel(const unsigned short* __restrict__ s2,
                                                  const int* __restrict__ csr_src,
                                                  const float* __restrict__ csr_val,
                                                  const int* __restrict__ row_ptr,
                                                  const float* __restrict__ b2,
                                                  float* __restrict__ out) {
    int d = blockIdx.x;
    int l = threadIdx.x;
    int e0 = row_ptr[d], e1 = row_ptr[d + 1];
    f32x4 a0 = ((const f32x4*)b2)[l * 2];
    f32x4 a1 = ((const f32x4*)b2)[l * 2 + 1];
    int e = e0;
    for (; e + 3 < e1; e += 4) {
        int s0 = csr_src[e], s1 = csr_src[e + 1], s2i = csr_src[e + 2], s3 = csr_src[e + 3];
        float v0 = csr_val[e], v1 = csr_val[e + 1], v2 = csr_val[e + 2], v3 = csr_val[e + 3];
        short8 w0 = *(const short8*)&s2[(size_t)s0 * NFEAT + l * 8];
        short8 w1 = *(const short8*)&s2[(size_t)s1 * NFEAT + l * 8];
        short8 w2 = *(const short8*)&s2[(size_t)s2i * NFEAT + l * 8];
        short8 w3 = *(const short8*)&s2[(size_t)s3 * NFEAT + l * 8];
#pragma unroll
        for (int j = 0; j < 4; ++j) {
            a0[j] += v0 * bf2f((unsigned short)w0[j]);
            a1[j] += v0 * bf2f((unsigned short)w0[4 + j]);
            a0[j] += v1 * bf2f((unsigned short)w1[j]);
            a1[j] += v1 * bf2f((unsigned short)w1[4 + j]);
            a0[j] += v2 * bf2f((unsigned short)w2[j]);
            a1[j] += v2 * bf2f((unsigned short)w2[4 + j]);
            a0[j] += v3 * bf2f((unsigned short)w3[j]);
            a1[j] += v3 * bf2f((unsigned short)w3[4 + j]);
        }
    }
    for (; e < e1; ++e) {
        int s0 = csr_src[e];
        float v0 = csr_val[e];
        short8 w0 = *(const short8*)&s2[(size_t)s0 * NFEAT + l * 8];
#pragma unroll
        for (int j = 0; j < 4; ++j) {
            a0[j] += v0 * bf2f((unsigned short)w0[j]);
            a1[j] += v0 * bf2f((unsigned short)w0[4 + j]);
        }
    }
    *(f32x4*)&out[(size_t)d * NFEAT + l * 8]     = a0;
    *(f32x4*)&out[(size_t)d * NFEAT + l * 8 + 4] = a1;
}

// ------------- fragment-packed register GEMM -------------
// Ap[mb][KT][64][8], Bp[nb-panels][KT][64][8]; each wave computes an
// independent 64x64 tile; every load is a contiguous 1KB wave-coalesced burst.
// No LDS / barriers in the main loop. 4 waves of a block share mi -> A-frags
// hit L1. EPI==1: bias+relu+dropout, output PACKED (A-layout for GEMM2) via
// wave-private LDS transpose. EPI==0: plain bf16 row-major output.

template <int EPI, int KT, int NW>
__global__ __launch_bounds__(256, 2) void gemm_pk(
    const unsigned short* __restrict__ Ap,
    const unsigned short* __restrict__ Bp,
    unsigned short* __restrict__ C,
    int M,
    const float* __restrict__ bias,
    const unsigned int* __restrict__ umask) {
    constexpr int N = NW * 64;

    // bijective XCD swizzle (m204): XCD-contiguous mi ranges
    const int nwg = gridDim.x;
    const int bid = blockIdx.x;
    const int q = nwg >> 3, r = nwg & 7;
    const int xcd = bid & 7, pos = bid >> 3;
    const int swz = (xcd < r ? xcd * (q + 1) : r * (q + 1) + (xcd - r) * q) + pos;

    const int wid = threadIdx.x >> 6;
    const int lane = threadIdx.x & 63;
    const int rl = lane & 15;
    const int kq = lane >> 4;

    const int wgid = swz * 4 + wid;
    const int mi = wgid / NW;      // 0..312
    const int ni = wgid % NW;

    const unsigned short* ab = Ap + (size_t)(mi * 4) * KT * 512 + lane * 8;
    const unsigned short* bb = Bp + (size_t)(ni * 4) * KT * 512 + lane * 8;

    f32x4 acc[4][4] = {};

#pragma unroll
    for (int kb = 0; kb < KT; ++kb) {
        short8 af[4], bf[4];
#pragma unroll
        for (int m = 0; m < 4; ++m)
            af[m] = *(const short8*)(ab + ((size_t)m * KT + kb) * 512);
#pragma unroll
        for (int n = 0; n < 4; ++n)
            bf[n] = *(const short8*)(bb + ((size_t)n * KT + kb) * 512);
#pragma unroll
        for (int m = 0; m < 4; ++m)
#pragma unroll
            for (int n = 0; n < 4; ++n)
                acc[m][n] = __builtin_amdgcn_mfma_f32_16x16x32_bf16(af[m], bf[n], acc[m][n], 0, 0, 0);
    }

    if constexpr (EPI == 1) {
        // bias + relu + dropout, then wave-private LDS transpose to packed layout
        __shared__ float ltr[4][64][36];   // pad 36: bank = (row*4 + col) % 32
        constexpr int KT2 = N / 32;
#pragma unroll
        for (int n2 = 0; n2 < 2; ++n2) {
#pragma unroll
            for (int m = 0; m < 4; ++m) {
#pragma unroll
                for (int nn = 0; nn < 2; ++nn) {
                    int n = n2 * 2 + nn;
                    int gc = ni * 64 + n * 16 + rl;
                    float bv = bias[gc];
#pragma unroll
                    for (int j = 0; j < 4; ++j) {
                        int gr = mi * 64 + m * 16 + kq * 4 + j;
                        int grm = gr < M ? gr : M - 1;
                        float v = acc[m][n][j] + bv;
                        v = v > 0.f ? v : 0.f;
                        unsigned w = umask[(size_t)grm * (N >> 5) + (gc >> 5)];
                        v = ((w >> (gc & 31)) & 1u) ? v * 2.0f : 0.0f;
                        ltr[wid][m * 16 + kq * 4 + j][nn * 16 + rl] = v;
                    }
                }
            }
            __builtin_amdgcn_s_waitcnt(0);  // lgkmcnt(0): LDS writes visible to own wave
#pragma unroll
            for (int m2 = 0; m2 < 4; ++m2) {
                int row = m2 * 16 + rl;
                f32x4 r0 = *(const f32x4*)&ltr[wid][row][kq * 8];
                f32x4 r1 = *(const f32x4*)&ltr[wid][row][kq * 8 + 4];
                short8 o;
#pragma unroll
                for (int j = 0; j < 4; ++j) {
                    o[j]     = (short)f2bf(r0[j]);
                    o[4 + j] = (short)f2bf(r1[j]);
                }
                int mbg = mi * 4 + m2;
                if (mbg * 16 < M) {
                    size_t dst = (((size_t)mbg * KT2 + (ni * 2 + n2)) * 64 + lane) * 8;
                    *(short8*)&C[dst] = o;
                }
            }
            __builtin_amdgcn_s_waitcnt(0);  // reads done before next n2 overwrites
        }
    } else {
        // plain bf16 row-major output
        const int crow = kq * 4;
#pragma unroll
        for (int m = 0; m < 4; ++m) {
#pragma unroll
            for (int n = 0; n < 4; ++n) {
                int gr0 = mi * 64 + m * 16 + crow;
                int gc = ni * 64 + n * 16 + rl;
#pragma unroll
                for (int j = 0; j < 4; ++j) {
                    int gr = gr0 + j;
                    if (gr < M)
                        C[(size_t)gr * N + gc] = f2bf(acc[m][n][j]);
                }
            }
        }
    }
}

// ---------------- launch ----------------

extern "C" void kernel_launch(void* const* d_in, const int* in_sizes, int n_in,
                              void* d_out, int out_size, void* d_ws, size_t ws_size,
                              hipStream_t stream) {
    const float* x        = (const float*)d_in[0];
    const float* W1       = (const float*)d_in[1];
    const float* b1       = (const float*)d_in[2];
    const float* W2       = (const float*)d_in[3];
    const float* b2       = (const float*)d_in[4];
    const float* adj_vals = (const float*)d_in[5];
    const float* u_drop   = (const float*)d_in[6];
    const int*   src      = (const int*)d_in[7];
    const int*   dst      = (const int*)d_in[8];
    float* out = (float*)d_out;

    char* p = (char*)d_ws;
    auto take = [&](size_t bytes) {
        char* q = p;
        p += (bytes + 255) & ~(size_t)255;
        return q;
    };
    int* deg        = (int*)take((size_t)N_NODES * 4);
    int* row_ptr    = (int*)take((size_t)(N_NODES + 1) * 4);
    int* cursor     = (int*)take((size_t)N_NODES * 4);
    int* csr_src    = (int*)take((size_t)N_EDGES * 4);
    float* csr_val  = (float*)take((size_t)N_EDGES * 4);
    unsigned short* w1p   = (unsigned short*)take((size_t)NFEAT * NHID * 2);
    unsigned short* w2p   = (unsigned short*)take((size_t)NFEAT * NHID * 2);
    unsigned short* xbf   = (unsigned short*)take((size_t)N_NODES * NFEAT * 2);
    unsigned short* a1p   = (unsigned short*)take((size_t)MBTOT * (NFEAT / 32) * 1024);
    unsigned short* a2p   = (unsigned short*)take((size_t)MBTOT * (NHID / 32) * 1024);
    unsigned short* s2buf = (unsigned short*)take((size_t)N_NODES * NFEAT * 2);
    unsigned int* umask   = (unsigned int*)take((size_t)N_NODES * (NHID / 32) * 4);

    hipMemsetAsync(deg, 0, (size_t)N_NODES * 4, stream);
    hist_kernel<<<(N_EDGES + 255) / 256, 256, 0, stream>>>(dst, deg, N_EDGES);
    scan_kernel<<<1, 1024, 0, stream>>>(deg, row_ptr, cursor, N_NODES);
    fill_kernel<<<(N_EDGES + 255) / 256, 256, 0, stream>>>(src, dst, adj_vals, cursor,
                                                           csr_src, csr_val, N_EDGES);
    transpose_cvt_pk<<<(NFEAT / 32) * (NHID / 32), 256, 0, stream>>>(W1, w1p, NFEAT, NHID);
    transpose_cvt_pk<<<(NHID / 32) * (NFEAT / 32), 256, 0, stream>>>(W2, w2p, NHID, NFEAT);
    cvt_bf16_kernel<<<(N_NODES * NFEAT / 8 + 255) / 256, 256, 0, stream>>>(
        x, xbf, N_NODES * NFEAT / 8);
    mask_kernel<<<N_NODES * NHID / 1024, 256, 0, stream>>>(u_drop, umask);

    agg1_kernel<<<N_NODES, 64, 0, stream>>>(xbf, csr_src, csr_val, row_ptr, a1p);

    const int mwaves = 313;  // ceil(20000/64)
    // GEMM1: [20000,512] x [512,1024] -> packed a2p
    gemm_pk<1, NFEAT / 32, NHID / 64><<<mwaves * (NHID / 64) / 4, 256, 0, stream>>>(
        a1p, w1p, a2p, N_NODES, b1, umask);
    // GEMM2: [20000,1024] x [1024,512] -> row-major s2buf
    gemm_pk<0, NHID / 32, NFEAT / 64><<<mwaves * (NFEAT / 64) / 4, 256, 0, stream>>>(
        a2p, w2p, s2buf, N_NODES, nullptr, nullptr);

    agg2_kernel<<<N_NODES, 64, 0, stream>>>(s2buf, csr_src, csr_val, row_ptr, b2, out);
}